// Round 10
// baseline (280.459 us; speedup 1.0000x reference)
//
#include <hip/hip_runtime.h>
#include <hip/hip_bf16.h>

typedef float  f32x4  __attribute__((ext_vector_type(4)));
typedef __bf16 bf16x4 __attribute__((ext_vector_type(4)));
typedef __bf16 bf16x8 __attribute__((ext_vector_type(8)));

#define B_SZ  64
#define NTOK  341
#define DM    768
#define NH    12
#define HD    64
#define MTOT  (B_SZ*NTOK)  // 21824
#define MP    21888
#define EQKV  2304

#define EXP2F(x) __builtin_amdgcn_exp2f(x)

__device__ __forceinline__ void gload_lds16(const __bf16* g, void* l) {
    __builtin_amdgcn_global_load_lds(
        (const __attribute__((address_space(1))) void*)g,
        (__attribute__((address_space(3))) void*)l, 16, 0, 0);
}

// ---------------- fp32 -> bf16 convert ----------------
__global__ void cvt_kernel(const float* __restrict__ in, __bf16* __restrict__ out, int n4) {
    int i = blockIdx.x * blockDim.x + threadIdx.x;
    const int stride = gridDim.x * blockDim.x;
    for (; i < n4; i += stride) {
        const float4 f = ((const float4*)in)[i];
        bf16x4 v;
        v[0] = (__bf16)f.x; v[1] = (__bf16)f.y; v[2] = (__bf16)f.z; v[3] = (__bf16)f.w;
        ((bf16x4*)out)[i] = v;
    }
}

// ---------------- 256x256xBK64 GEMM, 8 waves, 8x4 frags/wave ----------------
// XCD-chunked 1-D grid (n-fastest), 2-phase dbuf prefetch, packed epilogue.
template <int EPI, int EN, int NT>   // EN = output row-stride, NT = n-tiles
__global__ __launch_bounds__(512, 2) void gemm256(
    const __bf16* __restrict__ A, const __bf16* __restrict__ Bw,
    const float* __restrict__ bias,
    __bf16* __restrict__ obf, float* __restrict__ of32)
{
    __shared__ __bf16 As[2][256 * 64];   // 2 x 32 KiB
    __shared__ __bf16 Bs[2][256 * 64];   // 2 x 32 KiB  (128 KiB total)

    const int tid  = threadIdx.x;
    const int lane = tid & 63;
    const int w    = tid >> 6;     // 0..7
    const int wm   = w >> 2;       // 0..1  (M half)
    const int wn   = w & 3;        // 0..3  (N quarter)
    const int qi   = lane & 15;
    const int g    = lane >> 4;

    const int nwg = gridDim.x;
    const int bid = blockIdx.x;
    const int qq = nwg >> 3, rr = nwg & 7;
    const int xcd = bid & 7, idx = bid >> 3;
    const int wg = (xcd < rr ? xcd * (qq + 1) : rr * (qq + 1) + (xcd - rr) * qq) + idx;
    const int mtile = wg / NT;
    const int ntile = wg % NT;
    const long a_row0 = (long)mtile * 256;
    const long n0     = (long)ntile * 256;

    // staging: 4 instr per operand per wave; chunk = (it*8+w)*64 + lane
    const int slot = lane & 7;
    const __bf16* aP[4];
    const __bf16* bP[4];
#pragma unroll
    for (int it = 0; it < 4; ++it) {
        const int lrow = (it * 8 + w) * 8 + (lane >> 3);          // 0..255
        const int scol = (slot ^ (lrow & 7)) * 8;                 // rule-21 source swizzle
        aP[it] = A + (a_row0 + lrow) * DM + scol;
        // gamma permute: LDS row l holds global col n0 + gamma(l); packed epilogue
        const int gcol = (lrow & 0xC0) | ((lrow & 15) << 2) | ((lrow >> 4) & 3);
        bP[it] = Bw + (n0 + gcol) * DM + scol;
    }

    const f32x4 fzero = {0.f, 0.f, 0.f, 0.f};
    f32x4 acc[8][4];
#pragma unroll
    for (int i = 0; i < 8; ++i)
#pragma unroll
        for (int j = 0; j < 4; ++j) acc[i][j] = fzero;

#define STAGE(P, K0) do { \
    _Pragma("unroll") for (int it = 0; it < 4; ++it) { \
        gload_lds16(aP[it] + (K0), (char*)(&As[P][0]) + (it * 8 + w) * 1024); \
        gload_lds16(bP[it] + (K0), (char*)(&Bs[P][0]) + (it * 8 + w) * 1024); \
    } } while (0)

    STAGE(0, 0);
    __syncthreads();

    int cur = 0;
    for (int k0 = 0; k0 < DM; k0 += 64) {
        if (k0 + 64 < DM) STAGE(cur ^ 1, k0 + 64);   // prefetch: lands during this step's MFMA

        const __bf16* pA = &As[cur][0];
        const __bf16* pB = &Bs[cur][0];
        bf16x8 af[8][2], bfr[4][2];
#pragma unroll
        for (int i = 0; i < 8; ++i) {
            const int fr = wm * 128 + i * 16 + qi;
#pragma unroll
            for (int ks = 0; ks < 2; ++ks)
                af[i][ks] = *(const bf16x8*)(pA + fr * 64 + (((ks << 2) + g) ^ (fr & 7)) * 8);
        }
#pragma unroll
        for (int j = 0; j < 4; ++j) {
            const int frb = wn * 64 + j * 16 + qi;
#pragma unroll
            for (int ks = 0; ks < 2; ++ks)
                bfr[j][ks] = *(const bf16x8*)(pB + frb * 64 + (((ks << 2) + g) ^ (frb & 7)) * 8);
        }
#pragma unroll
        for (int ks = 0; ks < 2; ++ks)
#pragma unroll
            for (int j = 0; j < 4; ++j)
#pragma unroll
                for (int i = 0; i < 8; ++i)
                    acc[i][j] = __builtin_amdgcn_mfma_f32_16x16x32_bf16(
                        af[i][ks], bfr[j][ks], acc[i][j], 0, 0, 0);

        __syncthreads();
        cur ^= 1;
    }
#undef STAGE

    // packed epilogue: lane's 4 j-values are 4 consecutive output columns
    const long ge0 = n0 + wn * 64 + qi * 4;
    const float4 b4 = *(const float4*)(bias + ge0);
    const float mul = (EPI == 0 && n0 < DM) ? 0.125f * 1.44269504f : 1.f;
#pragma unroll
    for (int i = 0; i < 8; ++i) {
#pragma unroll
        for (int r = 0; r < 4; ++r) {
            const long m = a_row0 + wm * 128 + i * 16 + g * 4 + r;
            if (m < MTOT) {
                if (EPI == 0) {
                    bf16x4 pv;
                    pv[0] = (__bf16)((acc[i][0][r] + b4.x) * mul);
                    pv[1] = (__bf16)((acc[i][1][r] + b4.y) * mul);
                    pv[2] = (__bf16)((acc[i][2][r] + b4.z) * mul);
                    pv[3] = (__bf16)((acc[i][3][r] + b4.w) * mul);
                    *(bf16x4*)(obf + m * EN + ge0) = pv;
                } else {
                    float4 o;
                    o.x = acc[i][0][r] + b4.x;
                    o.y = acc[i][1][r] + b4.y;
                    o.z = acc[i][2][r] + b4.z;
                    o.w = acc[i][3][r] + b4.w;
                    *(float4*)(of32 + m * EN + ge0) = o;
                }
            }
        }
    }
}

// ---------------- attention: streaming (online, no-max) softmax ----------------
// (unchanged from round 9)
template <int NJ>
__device__ __forceinline__ void attn_group(
    const __bf16* __restrict__ qkv, const char* vL, __bf16* __restrict__ ao,
    long rowb, int h, int q0, int qi, int g)
{
    int qrow = q0 + qi; if (qrow > NTOK - 1) qrow = NTOK - 1;
    const __bf16* qsrc = qkv + (rowb + qrow) * EQKV + h * HD + g * 8;
    const bf16x8 qf0 = *(const bf16x8*)(qsrc);
    const bf16x8 qf1 = *(const bf16x8*)(qsrc + 32);

    const int qg = q0 + qi;
    int limit;
    if (qg == 0)       limit = NTOK;
    else if (qg < 5)   limit = 5;
    else if (qg < 21)  limit = 21;
    else if (qg < 85)  limit = 85;
    else               limit = NTOK;

    const f32x4 fzero = {0.f, 0.f, 0.f, 0.f};
    f32x4 oacc[4] = {fzero, fzero, fzero, fzero};
    float sum = 0.f;

    const __bf16* kbase = qkv + rowb * EQKV + DM + h * HD + g * 8;
    const int xd = (qi & 7) ^ ((qi >> 3) & 7);

#pragma unroll 2
    for (int j = 0; j < NJ; ++j) {
        const int kr0 = 32 * j + qi;
        int kr1 = kr0 + 16; if (kr1 > NTOK - 1) kr1 = NTOK - 1;
        const __bf16* k0p = kbase + (long)kr0 * EQKV;
        const __bf16* k1p = kbase + (long)kr1 * EQKV;
        const bf16x8 k00 = *(const bf16x8*)(k0p);
        const bf16x8 k01 = *(const bf16x8*)(k0p + 32);
        const bf16x8 k10 = *(const bf16x8*)(k1p);
        const bf16x8 k11 = *(const bf16x8*)(k1p + 32);

        f32x4 s0 = __builtin_amdgcn_mfma_f32_16x16x32_bf16(k00, qf0, fzero, 0, 0, 0);
        s0 = __builtin_amdgcn_mfma_f32_16x16x32_bf16(k01, qf1, s0, 0, 0, 0);
        f32x4 s1 = __builtin_amdgcn_mfma_f32_16x16x32_bf16(k10, qf0, fzero, 0, 0, 0);
        s1 = __builtin_amdgcn_mfma_f32_16x16x32_bf16(k11, qf1, s1, 0, 0, 0);

        bf16x8 pf;
#pragma unroll
        for (int r = 0; r < 4; ++r) {
            const int k0i = 32 * j + g * 4 + r;
            const float p0 = (k0i < limit) ? EXP2F(s0[r]) : 0.f;
            sum += p0; pf[r] = (__bf16)p0;
            const int k1i = k0i + 16;
            const float p1 = (k1i < limit) ? EXP2F(s1[r]) : 0.f;
            sum += p1; pf[4 + r] = (__bf16)p1;
        }

#pragma unroll
        for (int db = 0; db < 4; ++db) {
            const int d  = db * 16 + qi;
            const int sp = (4 * j + g) ^ xd ^ ((2 * db) & 7);
            const bf16x8 vf = *(const bf16x8*)(vL + d * 768 + sp * 16);
            oacc[db] = __builtin_amdgcn_mfma_f32_16x16x32_bf16(vf, pf, oacc[db], 0, 0, 0);
        }
    }

    sum += __shfl_xor(sum, 16);
    sum += __shfl_xor(sum, 32);
    const float rinv = 1.f / sum;

    if (qg < NTOK) {
        const long orow = (rowb + qg) * DM + h * HD;
#pragma unroll
        for (int db = 0; db < 4; ++db) {
            bf16x4 pv;
#pragma unroll
            for (int r = 0; r < 4; ++r) pv[r] = (__bf16)(oacc[db][r] * rinv);
            *(bf16x4*)(ao + orow + db * 16 + g * 4) = pv;
        }
    }
}

__global__ __launch_bounds__(512) void attn_kernel(
    const __bf16* __restrict__ qkv, __bf16* __restrict__ ao)
{
    const int h = blockIdx.x;
    const int b = blockIdx.y;
    const long rowb = (long)b * NTOK;

    __shared__ char vL[64 * 768];

    const int tid  = threadIdx.x;
    const int lane = tid & 63;
    const int w    = tid >> 6;

#pragma unroll
    for (int it = 0; it < 6; ++it) {
        const int c = it * 512 + tid;
        if (c < 2816) {
            const int n  = c >> 3;
            const int dc = (c & 7) << 3;
            bf16x8 e;
            if (n < NTOK) e = *(const bf16x8*)(qkv + (rowb + n) * EQKV + 1536 + h * HD + dc);
            else { e[0]=e[1]=e[2]=e[3]=e[4]=e[5]=e[6]=e[7] = (__bf16)0.f; }
            const int s   = ((n >> 5) << 2) | ((n >> 2) & 3);
            const int off = (((n >> 4) & 1) << 3) | ((n & 3) << 1);
            const int x   = c & 7;
#pragma unroll
            for (int i = 0; i < 8; ++i) {
                const int sp = s ^ i ^ x;
                *(__bf16*)(vL + (dc + i) * 768 + sp * 16 + off) = e[i];
            }
        }
    }
    __syncthreads();

    const int g  = lane >> 4;
    const int qi = lane & 15;

    for (int gi = w; gi < 22; gi += 8) {
        const int q0 = gi * 16;
        if (gi >= 1 && gi <= 4)
            attn_group<3>(qkv, vL, ao, rowb, h, q0, qi, g);
        else
            attn_group<11>(qkv, vL, ao, rowb, h, q0, qi, g);
    }
}

extern "C" void kernel_launch(void* const* d_in, const int* in_sizes, int n_in,
                              void* d_out, int out_size, void* d_ws, size_t ws_size,
                              hipStream_t stream) {
    const float* x      = (const float*)d_in[0];
    const float* qkv_w  = (const float*)d_in[1];
    const float* qkv_b  = (const float*)d_in[2];
    const float* proj_w = (const float*)d_in[3];
    const float* proj_b = (const float*)d_in[4];
    float* out = (float*)d_out;

    char* ws = (char*)d_ws;
    constexpr size_t XB_BYTES  = (size_t)MP * DM * 2;
    constexpr size_t WQ_OFF    = XB_BYTES;
    constexpr size_t WP_OFF    = WQ_OFF + (size_t)EQKV * DM * 2;
    constexpr size_t QKV_OFF   = WP_OFF + (size_t)DM * DM * 2;

    __bf16* xb  = (__bf16*)(ws);           // x bf16 [MP,768]; reused as attn-out
    __bf16* wq  = (__bf16*)(ws + WQ_OFF);
    __bf16* wp  = (__bf16*)(ws + WP_OFF);
    __bf16* qkv = (__bf16*)(ws + QKV_OFF); // [MTOT, 2304] bf16

    cvt_kernel<<<2048, 256, 0, stream>>>(x,      xb, MTOT * DM / 4);
    cvt_kernel<<<1728, 256, 0, stream>>>(qkv_w,  wq, EQKV * DM / 4);
    cvt_kernel<<<576,  256, 0, stream>>>(proj_w, wp, DM * DM / 4);

    gemm256<0, EQKV, 9><<<86 * 9, 512, 0, stream>>>(xb, wq, qkv_b, qkv, nullptr);
    attn_kernel<<<dim3(NH, B_SZ), 512, 0, stream>>>(qkv, xb);
    gemm256<1, DM, 3><<<86 * 3, 512, 0, stream>>>(xb, wp, proj_b, nullptr, out);
}

// Round 11
// 239.750 us; speedup vs baseline: 1.1698x; 1.1698x over previous
//
#include <hip/hip_runtime.h>
#include <hip/hip_bf16.h>

typedef float  f32x4  __attribute__((ext_vector_type(4)));
typedef __bf16 bf16x4 __attribute__((ext_vector_type(4)));
typedef __bf16 bf16x8 __attribute__((ext_vector_type(8)));

#define B_SZ  64
#define NTOK  341
#define DM    768
#define NH    12
#define HD    64
#define MTOT  (B_SZ*NTOK)  // 21824
#define MP    21888
#define EQKV  2304

#define EXP2F(x) __builtin_amdgcn_exp2f(x)

__device__ __forceinline__ void gload_lds16(const __bf16* g, void* l) {
    __builtin_amdgcn_global_load_lds(
        (const __attribute__((address_space(1))) void*)g,
        (__attribute__((address_space(3))) void*)l, 16, 0, 0);
}

// ---------------- fp32 -> bf16 convert ----------------
__global__ void cvt_kernel(const float* __restrict__ in, __bf16* __restrict__ out, int n4) {
    int i = blockIdx.x * blockDim.x + threadIdx.x;
    const int stride = gridDim.x * blockDim.x;
    for (; i < n4; i += stride) {
        const float4 f = ((const float4*)in)[i];
        bf16x4 v;
        v[0] = (__bf16)f.x; v[1] = (__bf16)f.y; v[2] = (__bf16)f.z; v[3] = (__bf16)f.w;
        ((bf16x4*)out)[i] = v;
    }
}

// ---------------- 128x128xBK64 GEMM (r9 config: best known) ----------------
template <int EPI, int EN, int NT>   // EN = output row-stride
__global__ __launch_bounds__(256) void gemm128(
    const __bf16* __restrict__ A, const __bf16* __restrict__ Bw,
    const float* __restrict__ bias,
    __bf16* __restrict__ obf, float* __restrict__ of32)
{
    __shared__ __bf16 As[2][128 * 64];
    __shared__ __bf16 Bs[2][128 * 64];

    const int tid  = threadIdx.x;
    const int lane = tid & 63;
    const int w    = tid >> 6;
    const int wm   = w >> 1, wn = w & 1;
    const int qi   = lane & 15;
    const int g    = lane >> 4;

    const int nwg = gridDim.x;
    const int bid = blockIdx.x;
    const int qq = nwg >> 3, rr = nwg & 7;
    const int xcd = bid & 7, idx = bid >> 3;
    const int wg = (xcd < rr ? xcd * (qq + 1) : rr * (qq + 1) + (xcd - rr) * qq) + idx;
    const int mtile = wg / NT;
    const int ntile = wg % NT;
    const long a_row0 = (long)mtile * 128;
    const long n0     = (long)ntile * 128;

    const int slot = lane & 7;
    const __bf16* aP[4];
    const __bf16* bP[4];
#pragma unroll
    for (int it = 0; it < 4; ++it) {
        const int lrow = it * 32 + w * 8 + (lane >> 3);
        const int scol = (slot ^ (lrow & 7)) * 8;
        aP[it] = A + (a_row0 + lrow) * DM + scol;
        const int gcol = (lrow & 64) | ((lrow & 15) << 2) | ((lrow >> 4) & 3);
        bP[it] = Bw + (n0 + gcol) * DM + scol;
    }

    const f32x4 fzero = {0.f, 0.f, 0.f, 0.f};
    f32x4 acc[4][4];
#pragma unroll
    for (int i = 0; i < 4; ++i)
#pragma unroll
        for (int j = 0; j < 4; ++j) acc[i][j] = fzero;

#define STAGE(P, K0) do { \
    _Pragma("unroll") for (int it = 0; it < 4; ++it) { \
        gload_lds16(aP[it] + (K0), (char*)(&As[P][0]) + it * 4096 + w * 1024); \
        gload_lds16(bP[it] + (K0), (char*)(&Bs[P][0]) + it * 4096 + w * 1024); \
    } } while (0)

    STAGE(0, 0);
    __syncthreads();

    int cur = 0;
    for (int k0 = 0; k0 < DM; k0 += 64) {
        if (k0 + 64 < DM) STAGE(cur ^ 1, k0 + 64);

        const __bf16* pA = &As[cur][0];
        const __bf16* pB = &Bs[cur][0];
        bf16x8 af[4][2], bfr[4][2];
#pragma unroll
        for (int i = 0; i < 4; ++i) {
            const int fr = wm * 64 + i * 16 + qi;
#pragma unroll
            for (int ks = 0; ks < 2; ++ks)
                af[i][ks] = *(const bf16x8*)(pA + fr * 64 + (((ks << 2) + g) ^ (fr & 7)) * 8);
        }
#pragma unroll
        for (int j = 0; j < 4; ++j) {
            const int frb = wn * 64 + j * 16 + qi;
#pragma unroll
            for (int ks = 0; ks < 2; ++ks)
                bfr[j][ks] = *(const bf16x8*)(pB + frb * 64 + (((ks << 2) + g) ^ (frb & 7)) * 8);
        }
#pragma unroll
        for (int ks = 0; ks < 2; ++ks)
#pragma unroll
            for (int j = 0; j < 4; ++j)
#pragma unroll
                for (int i = 0; i < 4; ++i)
                    acc[i][j] = __builtin_amdgcn_mfma_f32_16x16x32_bf16(
                        af[i][ks], bfr[j][ks], acc[i][j], 0, 0, 0);

        __syncthreads();
        cur ^= 1;
    }
#undef STAGE

    const long ge0 = n0 + wn * 64 + qi * 4;
    const float4 b4 = *(const float4*)(bias + ge0);
    const float mul = (EPI == 0 && (n0 + wn * 64) < DM) ? 0.125f * 1.44269504f : 1.f;
#pragma unroll
    for (int i = 0; i < 4; ++i) {
#pragma unroll
        for (int r = 0; r < 4; ++r) {
            const long m = a_row0 + wm * 64 + i * 16 + g * 4 + r;
            if (m < MTOT) {
                if (EPI == 0) {
                    bf16x4 pv;
                    pv[0] = (__bf16)((acc[i][0][r] + b4.x) * mul);
                    pv[1] = (__bf16)((acc[i][1][r] + b4.y) * mul);
                    pv[2] = (__bf16)((acc[i][2][r] + b4.z) * mul);
                    pv[3] = (__bf16)((acc[i][3][r] + b4.w) * mul);
                    *(bf16x4*)(obf + m * EN + ge0) = pv;
                } else {
                    float4 o;
                    o.x = acc[i][0][r] + b4.x;
                    o.y = acc[i][1][r] + b4.y;
                    o.z = acc[i][2][r] + b4.z;
                    o.w = acc[i][3][r] + b4.w;
                    *(float4*)(of32 + m * EN + ge0) = o;
                }
            }
        }
    }
}

// ---------------- attention: 3-way q-group ILP, shared K/V loads ----------------
// qkv layout: [M, 2304]; q = cols 0..767 (pre-scaled by 0.125*log2e), k = +768, v = +1536.
// One block per (b,h); 8 waves; each wave holds 3 q-groups (gi = w, w+8, w+16) and
// walks k ONCE: per j-tile, K loaded once (shared x3), vf loaded once per db (shared x3),
// 3 independent QK->exp->PV chains give in-wave ILP. Uniform NJ=11; masking via limit.
__global__ __launch_bounds__(512) void attn_kernel(
    const __bf16* __restrict__ qkv, __bf16* __restrict__ ao)
{
    const int h = blockIdx.x;
    const int b = blockIdx.y;
    const long rowb = (long)b * NTOK;

    __shared__ char vL[64 * 768];   // 48 KiB, V^T fragment-order, double-XOR swizzle

    const int tid  = threadIdx.x;
    const int lane = tid & 63;
    const int w    = tid >> 6;   // 0..7

    // stage V: 352 n-rows x 8 d-chunks = 2816 pieces
#pragma unroll
    for (int it = 0; it < 6; ++it) {
        const int c = it * 512 + tid;
        if (c < 2816) {
            const int n  = c >> 3;
            const int dc = (c & 7) << 3;
            bf16x8 e;
            if (n < NTOK) e = *(const bf16x8*)(qkv + (rowb + n) * EQKV + 1536 + h * HD + dc);
            else { e[0]=e[1]=e[2]=e[3]=e[4]=e[5]=e[6]=e[7] = (__bf16)0.f; }
            const int s   = ((n >> 5) << 2) | ((n >> 2) & 3);
            const int off = (((n >> 4) & 1) << 3) | ((n & 3) << 1);
            const int x   = c & 7;
#pragma unroll
            for (int i = 0; i < 8; ++i) {
                const int sp = s ^ i ^ x;
                *(__bf16*)(vL + (dc + i) * 768 + sp * 16 + off) = e[i];
            }
        }
    }
    __syncthreads();

    const int g  = lane >> 4;
    const int qi = lane & 15;

    // per-slot persistent state (all constant-indexed -> registers)
    bf16x8 qf0[3], qf1[3];
    int   qg[3], limit[3];
#pragma unroll
    for (int s = 0; s < 3; ++s) {
        const int gi = w + 8 * s;            // gi >= 22 harmless: clamped row, store skipped
        const int q  = gi * 16 + qi;
        qg[s] = q;
        const int qrow = (q > NTOK - 1) ? (NTOK - 1) : q;
        const __bf16* qsrc = qkv + (rowb + qrow) * EQKV + h * HD + g * 8;
        qf0[s] = *(const bf16x8*)(qsrc);
        qf1[s] = *(const bf16x8*)(qsrc + 32);
        limit[s] = (q == 0) ? NTOK : (q < 5 ? 5 : (q < 21 ? 21 : (q < 85 ? 85 : NTOK)));
    }

    const f32x4 fzero = {0.f, 0.f, 0.f, 0.f};
    f32x4 oacc[3][4];
    float sum[3] = {0.f, 0.f, 0.f};
#pragma unroll
    for (int s = 0; s < 3; ++s)
#pragma unroll
        for (int db = 0; db < 4; ++db) oacc[s][db] = fzero;

    const __bf16* kbase = qkv + rowb * EQKV + DM + h * HD + g * 8;
    const int xd = (qi & 7) ^ ((qi >> 3) & 7);

    for (int j = 0; j < 11; ++j) {
        // ---- shared K loads for this 32-k tile
        const int kr0 = 32 * j + qi;                       // <= 335, in-bounds
        int kr1 = kr0 + 16; if (kr1 > NTOK - 1) kr1 = NTOK - 1;   // only j=10 clamps
        const __bf16* k0p = kbase + (long)kr0 * EQKV;
        const __bf16* k1p = kbase + (long)kr1 * EQKV;
        const bf16x8 k00 = *(const bf16x8*)(k0p);
        const bf16x8 k01 = *(const bf16x8*)(k0p + 32);
        const bf16x8 k10 = *(const bf16x8*)(k1p);
        const bf16x8 k11 = *(const bf16x8*)(k1p + 32);

        // ---- 3 independent QK -> exp -> pack chains
        bf16x8 pf[3];
#pragma unroll
        for (int s = 0; s < 3; ++s) {
            f32x4 s0 = __builtin_amdgcn_mfma_f32_16x16x32_bf16(k00, qf0[s], fzero, 0, 0, 0);
            s0 = __builtin_amdgcn_mfma_f32_16x16x32_bf16(k01, qf1[s], s0, 0, 0, 0);
            f32x4 s1 = __builtin_amdgcn_mfma_f32_16x16x32_bf16(k10, qf0[s], fzero, 0, 0, 0);
            s1 = __builtin_amdgcn_mfma_f32_16x16x32_bf16(k11, qf1[s], s1, 0, 0, 0);
#pragma unroll
            for (int r = 0; r < 4; ++r) {
                const int k0i = 32 * j + g * 4 + r;
                const float p0 = (k0i < limit[s]) ? EXP2F(s0[r]) : 0.f;
                sum[s] += p0; pf[s][r] = (__bf16)p0;
                const int k1i = k0i + 16;
                const float p1 = (k1i < limit[s]) ? EXP2F(s1[r]) : 0.f;
                sum[s] += p1; pf[s][4 + r] = (__bf16)p1;
            }
        }

        // ---- PV: vf loaded once per db, shared by all 3 slots
#pragma unroll
        for (int db = 0; db < 4; ++db) {
            const int d  = db * 16 + qi;
            const int sp = (4 * j + g) ^ xd ^ ((2 * db) & 7);
            const bf16x8 vf = *(const bf16x8*)(vL + d * 768 + sp * 16);
#pragma unroll
            for (int s = 0; s < 3; ++s)
                oacc[s][db] = __builtin_amdgcn_mfma_f32_16x16x32_bf16(
                    vf, pf[s], oacc[s][db], 0, 0, 0);
        }
    }

    // ---- normalize + store per slot
#pragma unroll
    for (int s = 0; s < 3; ++s) {
        float t = sum[s];
        t += __shfl_xor(t, 16);
        t += __shfl_xor(t, 32);
        const float rinv = 1.f / t;
        if (qg[s] < NTOK) {
            const long orow = (rowb + qg[s]) * DM + h * HD;
#pragma unroll
            for (int db = 0; db < 4; ++db) {
                bf16x4 pv;
#pragma unroll
                for (int r = 0; r < 4; ++r) pv[r] = (__bf16)(oacc[s][db][r] * rinv);
                *(bf16x4*)(ao + orow + db * 16 + g * 4) = pv;
            }
        }
    }
}

extern "C" void kernel_launch(void* const* d_in, const int* in_sizes, int n_in,
                              void* d_out, int out_size, void* d_ws, size_t ws_size,
                              hipStream_t stream) {
    const float* x      = (const float*)d_in[0];
    const float* qkv_w  = (const float*)d_in[1];
    const float* qkv_b  = (const float*)d_in[2];
    const float* proj_w = (const float*)d_in[3];
    const float* proj_b = (const float*)d_in[4];
    float* out = (float*)d_out;

    char* ws = (char*)d_ws;
    constexpr size_t XB_BYTES  = (size_t)MP * DM * 2;
    constexpr size_t WQ_OFF    = XB_BYTES;
    constexpr size_t WP_OFF    = WQ_OFF + (size_t)EQKV * DM * 2;
    constexpr size_t QKV_OFF   = WP_OFF + (size_t)DM * DM * 2;

    __bf16* xb  = (__bf16*)(ws);           // x bf16 [MP,768]; reused as attn-out
    __bf16* wq  = (__bf16*)(ws + WQ_OFF);
    __bf16* wp  = (__bf16*)(ws + WP_OFF);
    __bf16* qkv = (__bf16*)(ws + QKV_OFF); // [MTOT, 2304] bf16

    cvt_kernel<<<2048, 256, 0, stream>>>(x,      xb, MTOT * DM / 4);
    cvt_kernel<<<1728, 256, 0, stream>>>(qkv_w,  wq, EQKV * DM / 4);
    cvt_kernel<<<576,  256, 0, stream>>>(proj_w, wp, DM * DM / 4);

    gemm128<0, EQKV, 18><<<171 * 18, 256, 0, stream>>>(xb, wq, qkv_b, qkv, nullptr);
    attn_kernel<<<dim3(NH, B_SZ), 512, 0, stream>>>(qkv, xb);
    gemm128<1, DM, 6><<<171 * 6, 256, 0, stream>>>(xb, wp, proj_b, nullptr, out);
}

// Round 12
// 224.786 us; speedup vs baseline: 1.2477x; 1.0666x over previous
//
#include <hip/hip_runtime.h>
#include <hip/hip_bf16.h>

typedef float  f32x4  __attribute__((ext_vector_type(4)));
typedef __bf16 bf16x4 __attribute__((ext_vector_type(4)));
typedef __bf16 bf16x8 __attribute__((ext_vector_type(8)));

#define B_SZ  64
#define NTOK  341
#define DM    768
#define NH    12
#define HD    64
#define MTOT  (B_SZ*NTOK)  // 21824
#define MP    21888
#define EQKV  2304

#define EXP2F(x) __builtin_amdgcn_exp2f(x)

__device__ __forceinline__ void gload_lds16(const __bf16* g, void* l) {
    __builtin_amdgcn_global_load_lds(
        (const __attribute__((address_space(1))) void*)g,
        (__attribute__((address_space(3))) void*)l, 16, 0, 0);
}

// ---------------- fused fp32 -> bf16 convert (x, qkv_w, proj_w in one launch) ----------------
__global__ void cvt3_kernel(const float* __restrict__ x,  __bf16* __restrict__ xb,
                            const float* __restrict__ wqf, __bf16* __restrict__ wq,
                            const float* __restrict__ wpf, __bf16* __restrict__ wp) {
    constexpr int N1 = MTOT * DM / 4;
    constexpr int N2 = EQKV * DM / 4;
    constexpr int N3 = DM * DM / 4;
    int i = blockIdx.x * blockDim.x + threadIdx.x;
    const int stride = gridDim.x * blockDim.x;
    for (; i < N1 + N2 + N3; i += stride) {
        const float* src; __bf16* dst; int k;
        if (i < N1)           { src = x;   dst = xb; k = i; }
        else if (i < N1 + N2) { src = wqf; dst = wq; k = i - N1; }
        else                  { src = wpf; dst = wp; k = i - N1 - N2; }
        const float4 f = ((const float4*)src)[k];
        bf16x4 v;
        v[0] = (__bf16)f.x; v[1] = (__bf16)f.y; v[2] = (__bf16)f.z; v[3] = (__bf16)f.w;
        ((bf16x4*)dst)[k] = v;
    }
}

// ---------------- 128x128xBK64 GEMM (frozen r9/r11 config) ----------------
template <int EPI, int EN, int NT>   // EN = output row-stride
__global__ __launch_bounds__(256) void gemm128(
    const __bf16* __restrict__ A, const __bf16* __restrict__ Bw,
    const float* __restrict__ bias,
    __bf16* __restrict__ obf, float* __restrict__ of32)
{
    __shared__ __bf16 As[2][128 * 64];
    __shared__ __bf16 Bs[2][128 * 64];

    const int tid  = threadIdx.x;
    const int lane = tid & 63;
    const int w    = tid >> 6;
    const int wm   = w >> 1, wn = w & 1;
    const int qi   = lane & 15;
    const int g    = lane >> 4;

    const int nwg = gridDim.x;
    const int bid = blockIdx.x;
    const int qq = nwg >> 3, rr = nwg & 7;
    const int xcd = bid & 7, idx = bid >> 3;
    const int wg = (xcd < rr ? xcd * (qq + 1) : rr * (qq + 1) + (xcd - rr) * qq) + idx;
    const int mtile = wg / NT;
    const int ntile = wg % NT;
    const long a_row0 = (long)mtile * 128;
    const long n0     = (long)ntile * 128;

    const int slot = lane & 7;
    const __bf16* aP[4];
    const __bf16* bP[4];
#pragma unroll
    for (int it = 0; it < 4; ++it) {
        const int lrow = it * 32 + w * 8 + (lane >> 3);
        const int scol = (slot ^ (lrow & 7)) * 8;
        aP[it] = A + (a_row0 + lrow) * DM + scol;
        const int gcol = (lrow & 64) | ((lrow & 15) << 2) | ((lrow >> 4) & 3);
        bP[it] = Bw + (n0 + gcol) * DM + scol;
    }

    const f32x4 fzero = {0.f, 0.f, 0.f, 0.f};
    f32x4 acc[4][4];
#pragma unroll
    for (int i = 0; i < 4; ++i)
#pragma unroll
        for (int j = 0; j < 4; ++j) acc[i][j] = fzero;

#define STAGE(P, K0) do { \
    _Pragma("unroll") for (int it = 0; it < 4; ++it) { \
        gload_lds16(aP[it] + (K0), (char*)(&As[P][0]) + it * 4096 + w * 1024); \
        gload_lds16(bP[it] + (K0), (char*)(&Bs[P][0]) + it * 4096 + w * 1024); \
    } } while (0)

    STAGE(0, 0);
    __syncthreads();

    int cur = 0;
    for (int k0 = 0; k0 < DM; k0 += 64) {
        if (k0 + 64 < DM) STAGE(cur ^ 1, k0 + 64);

        const __bf16* pA = &As[cur][0];
        const __bf16* pB = &Bs[cur][0];
        bf16x8 af[4][2], bfr[4][2];
#pragma unroll
        for (int i = 0; i < 4; ++i) {
            const int fr = wm * 64 + i * 16 + qi;
#pragma unroll
            for (int ks = 0; ks < 2; ++ks)
                af[i][ks] = *(const bf16x8*)(pA + fr * 64 + (((ks << 2) + g) ^ (fr & 7)) * 8);
        }
#pragma unroll
        for (int j = 0; j < 4; ++j) {
            const int frb = wn * 64 + j * 16 + qi;
#pragma unroll
            for (int ks = 0; ks < 2; ++ks)
                bfr[j][ks] = *(const bf16x8*)(pB + frb * 64 + (((ks << 2) + g) ^ (frb & 7)) * 8);
        }
#pragma unroll
        for (int ks = 0; ks < 2; ++ks)
#pragma unroll
            for (int j = 0; j < 4; ++j)
#pragma unroll
                for (int i = 0; i < 4; ++i)
                    acc[i][j] = __builtin_amdgcn_mfma_f32_16x16x32_bf16(
                        af[i][ks], bfr[j][ks], acc[i][j], 0, 0, 0);

        __syncthreads();
        cur ^= 1;
    }
#undef STAGE

    const long ge0 = n0 + wn * 64 + qi * 4;
    const float4 b4 = *(const float4*)(bias + ge0);
    const float mul = (EPI == 0 && (n0 + wn * 64) < DM) ? 0.125f * 1.44269504f : 1.f;
#pragma unroll
    for (int i = 0; i < 4; ++i) {
#pragma unroll
        for (int r = 0; r < 4; ++r) {
            const long m = a_row0 + wm * 64 + i * 16 + g * 4 + r;
            if (m < MTOT) {
                if (EPI == 0) {
                    bf16x4 pv;
                    pv[0] = (__bf16)((acc[i][0][r] + b4.x) * mul);
                    pv[1] = (__bf16)((acc[i][1][r] + b4.y) * mul);
                    pv[2] = (__bf16)((acc[i][2][r] + b4.z) * mul);
                    pv[3] = (__bf16)((acc[i][3][r] + b4.w) * mul);
                    *(bf16x4*)(obf + m * EN + ge0) = pv;
                } else {
                    float4 o;
                    o.x = acc[i][0][r] + b4.x;
                    o.y = acc[i][1][r] + b4.y;
                    o.z = acc[i][2][r] + b4.z;
                    o.w = acc[i][3][r] + b4.w;
                    *(float4*)(of32 + m * EN + ge0) = o;
                }
            }
        }
    }
}

// ---------------- attention: 3-way q-group ILP + K register prefetch (T14) ----------------
// qkv layout: [M, 2304]; q = cols 0..767 (pre-scaled by 0.125*log2e), k = +768, v = +1536.
// One block per (b,h); 8 waves; each wave holds 3 q-groups (gi = w, w+8, w+16), walks k once.
// K tile j+1 is loaded into the alternate register buffer while tile j computes, so the
// ~700-cycle L3/HBM latency hides under QK/exp/PV work. First K tile + Q fragments are
// issued BEFORE __syncthreads so the V-staging drain covers their latency.
__global__ __launch_bounds__(512) void attn_kernel(
    const __bf16* __restrict__ qkv, __bf16* __restrict__ ao)
{
    const int h = blockIdx.x;
    const int b = blockIdx.y;
    const long rowb = (long)b * NTOK;

    __shared__ char vL[64 * 768];   // 48 KiB, V^T fragment-order, double-XOR swizzle

    const int tid  = threadIdx.x;
    const int lane = tid & 63;
    const int w    = tid >> 6;   // 0..7
    const int g    = lane >> 4;
    const int qi   = lane & 15;

    const __bf16* kbase = qkv + rowb * EQKV + DM + h * HD + g * 8;

    // ---- issue Q loads + first K tile BEFORE staging barrier (latency hidden by drain)
    bf16x8 qf0[3], qf1[3];
    int qg[3], limit[3];
#pragma unroll
    for (int s = 0; s < 3; ++s) {
        const int gi = w + 8 * s;            // gi >= 22 harmless: clamped row, store skipped
        const int q  = gi * 16 + qi;
        qg[s] = q;
        const int qrow = (q > NTOK - 1) ? (NTOK - 1) : q;
        const __bf16* qsrc = qkv + (rowb + qrow) * EQKV + h * HD + g * 8;
        qf0[s] = *(const bf16x8*)(qsrc);
        qf1[s] = *(const bf16x8*)(qsrc + 32);
        limit[s] = (q == 0) ? NTOK : (q < 5 ? 5 : (q < 21 ? 21 : (q < 85 ? 85 : NTOK)));
    }

#define LOADK(BUF, J) do { \
    const int kr0_ = 32 * (J) + qi; \
    int kr1_ = kr0_ + 16; if (kr1_ > NTOK - 1) kr1_ = NTOK - 1; \
    const __bf16* k0p_ = kbase + (long)kr0_ * EQKV; \
    const __bf16* k1p_ = kbase + (long)kr1_ * EQKV; \
    BUF[0] = *(const bf16x8*)(k0p_); \
    BUF[1] = *(const bf16x8*)(k0p_ + 32); \
    BUF[2] = *(const bf16x8*)(k1p_); \
    BUF[3] = *(const bf16x8*)(k1p_ + 32); \
} while (0)

    bf16x8 kr[2][4];
    LOADK(kr[0], 0);

    // ---- stage V: 352 n-rows x 8 d-chunks = 2816 pieces
#pragma unroll
    for (int it = 0; it < 6; ++it) {
        const int c = it * 512 + tid;
        if (c < 2816) {
            const int n  = c >> 3;
            const int dc = (c & 7) << 3;
            bf16x8 e;
            if (n < NTOK) e = *(const bf16x8*)(qkv + (rowb + n) * EQKV + 1536 + h * HD + dc);
            else { e[0]=e[1]=e[2]=e[3]=e[4]=e[5]=e[6]=e[7] = (__bf16)0.f; }
            const int s   = ((n >> 5) << 2) | ((n >> 2) & 3);
            const int off = (((n >> 4) & 1) << 3) | ((n & 3) << 1);
            const int x   = c & 7;
#pragma unroll
            for (int i = 0; i < 8; ++i) {
                const int sp = s ^ i ^ x;
                *(__bf16*)(vL + (dc + i) * 768 + sp * 16 + off) = e[i];
            }
        }
    }
    __syncthreads();

    const f32x4 fzero = {0.f, 0.f, 0.f, 0.f};
    f32x4 oacc[3][4];
    float sum[3] = {0.f, 0.f, 0.f};
#pragma unroll
    for (int s = 0; s < 3; ++s)
#pragma unroll
        for (int db = 0; db < 4; ++db) oacc[s][db] = fzero;

    const int xd = (qi & 7) ^ ((qi >> 3) & 7);

#pragma unroll 2
    for (int j = 0; j < 11; ++j) {
        // prefetch next K tile into the alternate buffer (indices static under unroll-2)
        if (j + 1 < 11) LOADK(kr[(j + 1) & 1], j + 1);

        // ---- 3 independent QK -> exp -> pack chains on current buffer
        bf16x8 pf[3];
#pragma unroll
        for (int s = 0; s < 3; ++s) {
            f32x4 s0 = __builtin_amdgcn_mfma_f32_16x16x32_bf16(kr[j & 1][0], qf0[s], fzero, 0, 0, 0);
            s0 = __builtin_amdgcn_mfma_f32_16x16x32_bf16(kr[j & 1][1], qf1[s], s0, 0, 0, 0);
            f32x4 s1 = __builtin_amdgcn_mfma_f32_16x16x32_bf16(kr[j & 1][2], qf0[s], fzero, 0, 0, 0);
            s1 = __builtin_amdgcn_mfma_f32_16x16x32_bf16(kr[j & 1][3], qf1[s], s1, 0, 0, 0);
#pragma unroll
            for (int r = 0; r < 4; ++r) {
                const int k0i = 32 * j + g * 4 + r;
                const float p0 = (k0i < limit[s]) ? EXP2F(s0[r]) : 0.f;
                sum[s] += p0; pf[s][r] = (__bf16)p0;
                const int k1i = k0i + 16;
                const float p1 = (k1i < limit[s]) ? EXP2F(s1[r]) : 0.f;
                sum[s] += p1; pf[s][4 + r] = (__bf16)p1;
            }
        }

        // ---- PV: vf loaded once per db, shared by all 3 slots
#pragma unroll
        for (int db = 0; db < 4; ++db) {
            const int d  = db * 16 + qi;
            const int sp = (4 * j + g) ^ xd ^ ((2 * db) & 7);
            const bf16x8 vf = *(const bf16x8*)(vL + d * 768 + sp * 16);
#pragma unroll
            for (int s = 0; s < 3; ++s)
                oacc[s][db] = __builtin_amdgcn_mfma_f32_16x16x32_bf16(
                    vf, pf[s], oacc[s][db], 0, 0, 0);
        }
    }
#undef LOADK

    // ---- normalize + store per slot
#pragma unroll
    for (int s = 0; s < 3; ++s) {
        float t = sum[s];
        t += __shfl_xor(t, 16);
        t += __shfl_xor(t, 32);
        const float rinv = 1.f / t;
        if (qg[s] < NTOK) {
            const long orow = (rowb + qg[s]) * DM + h * HD;
#pragma unroll
            for (int db = 0; db < 4; ++db) {
                bf16x4 pv;
#pragma unroll
                for (int r = 0; r < 4; ++r) pv[r] = (__bf16)(oacc[s][db][r] * rinv);
                *(bf16x4*)(ao + orow + db * 16 + g * 4) = pv;
            }
        }
    }
}

extern "C" void kernel_launch(void* const* d_in, const int* in_sizes, int n_in,
                              void* d_out, int out_size, void* d_ws, size_t ws_size,
                              hipStream_t stream) {
    const float* x      = (const float*)d_in[0];
    const float* qkv_w  = (const float*)d_in[1];
    const float* qkv_b  = (const float*)d_in[2];
    const float* proj_w = (const float*)d_in[3];
    const float* proj_b = (const float*)d_in[4];
    float* out = (float*)d_out;

    char* ws = (char*)d_ws;
    constexpr size_t XB_BYTES  = (size_t)MP * DM * 2;
    constexpr size_t WQ_OFF    = XB_BYTES;
    constexpr size_t WP_OFF    = WQ_OFF + (size_t)EQKV * DM * 2;
    constexpr size_t QKV_OFF   = WP_OFF + (size_t)DM * DM * 2;

    __bf16* xb  = (__bf16*)(ws);           // x bf16 [MP,768]; reused as attn-out
    __bf16* wq  = (__bf16*)(ws + WQ_OFF);
    __bf16* wp  = (__bf16*)(ws + WP_OFF);
    __bf16* qkv = (__bf16*)(ws + QKV_OFF); // [MTOT, 2304] bf16

    cvt3_kernel<<<2048, 256, 0, stream>>>(x, xb, qkv_w, wq, proj_w, wp);

    gemm128<0, EQKV, 18><<<171 * 18, 256, 0, stream>>>(xb, wq, qkv_b, qkv, nullptr);
    attn_kernel<<<dim3(NH, B_SZ), 512, 0, stream>>>(qkv, xb);
    gemm128<1, DM, 6><<<171 * 6, 256, 0, stream>>>(xb, wp, proj_b, nullptr, out);
}